// Round 8
// baseline (1647.300 us; speedup 1.0000x reference)
//
#include <hip/hip_runtime.h>
#include <cstddef>
#include <cstdint>

// Stacked SimpleRNN, fp32.  B=512, T=512, F=78, hiddens 16/32/64/70, dense->5+softmax.
//
// Round-8 theory: the scan step is LATENCY-bound (serial chain: ds_write -> ds_read
// ~120cyc -> FMA chain -> tanh trans chain; VALUBusy 32%, all pipes idle).  Fix:
// R=2 independent batch rows per wave = two interleaved chains -> ILP hides the
// stalls.  rec64/rec70 get R=2 (+ xv hoisted to regs per chunk); fused_rec16/32
// are unchanged controls (already lane-amortized 4/2 rows per chain).
#define REC_ATTR __attribute__((amdgpu_waves_per_eu(1, 1)))

#define BB 512
#define TT 512
#define M_TOTAL (BB * TT)

// LDS-visibility sync WITHOUT a vmcnt drain (keeps global traffic in flight).
#define LDS_BARRIER() asm volatile("s_waitcnt lgkmcnt(0)\n\ts_barrier" ::: "memory")

__device__ __forceinline__ float tanh_fast(float x) {
  float ax = fabsf(x);
  float e = __expf(ax + ax);
  float r = 1.0f - 2.0f / (e + 1.0f);
  return (x >= 0.0f) ? r : -r;
}

__device__ __forceinline__ void fma4(float4& a, float s, const float4 w) {
  a.x = fmaf(s, w.x, a.x);
  a.y = fmaf(s, w.y, a.y);
  a.z = fmaf(s, w.z, a.z);
  a.w = fmaf(s, w.w, a.w);
}

// ---------------------------------------------------------------------------
// proj: out[M,N] = in[M,K] @ W[K,N] + b.  256 threads; 4x4 tile per thread.
// ---------------------------------------------------------------------------
template<int K, int N, int CG>
__global__ __launch_bounds__(256)
void proj_kernel(const float* __restrict__ in, const float* __restrict__ W,
                 const float* __restrict__ bias, float* __restrict__ out, int M)
{
  constexpr int NP = CG * 4;
  constexpr int RG = 256 / CG;
  __shared__ __align__(16) float wlds[K][NP];
  __shared__ __align__(16) float blds[NP];
  const int tid = threadIdx.x;
  for (int idx = tid; idx < K * NP; idx += 256) {
    int k = idx / NP, jj = idx - k * NP;
    wlds[k][jj] = (jj < N) ? W[k * N + jj] : 0.0f;
  }
  if (tid < NP) blds[tid] = (tid < N) ? bias[tid] : 0.0f;
  __syncthreads();

  const int c = tid % CG;
  const int rg = tid / CG;
  if (rg >= RG) return;
  const int j0 = c * 4;
  const long row0 = (long)blockIdx.x * (RG * 4) + (long)rg * 4;

  float4 b4 = *reinterpret_cast<const float4*>(&blds[j0]);
  float4 acc[4] = {b4, b4, b4, b4};
  const float* inp[4];
  bool rv[4];
  #pragma unroll
  for (int rr = 0; rr < 4; ++rr) {
    long rowi = row0 + rr;
    rv[rr] = rowi < M;
    inp[rr] = in + (rv[rr] ? rowi : 0) * (long)K;
  }

  int k = 0;
  for (; k + 4 <= K; k += 4) {
    float4 w0 = *reinterpret_cast<const float4*>(&wlds[k + 0][j0]);
    float4 w1 = *reinterpret_cast<const float4*>(&wlds[k + 1][j0]);
    float4 w2 = *reinterpret_cast<const float4*>(&wlds[k + 2][j0]);
    float4 w3 = *reinterpret_cast<const float4*>(&wlds[k + 3][j0]);
    #pragma unroll
    for (int rr = 0; rr < 4; ++rr) {
      float2 i0 = *reinterpret_cast<const float2*>(inp[rr] + k);
      float2 i1 = *reinterpret_cast<const float2*>(inp[rr] + k + 2);
      fma4(acc[rr], i0.x, w0);
      fma4(acc[rr], i0.y, w1);
      fma4(acc[rr], i1.x, w2);
      fma4(acc[rr], i1.y, w3);
    }
  }
  for (; k < K; ++k) {
    float4 w0 = *reinterpret_cast<const float4*>(&wlds[k][j0]);
    #pragma unroll
    for (int rr = 0; rr < 4; ++rr) fma4(acc[rr], inp[rr][k], w0);
  }

  #pragma unroll
  for (int rr = 0; rr < 4; ++rr) {
    if (!rv[rr]) continue;
    long obase = (row0 + rr) * (long)N + j0;
    if constexpr ((N % 4) == 0) {
      *reinterpret_cast<float4*>(&out[obase]) = acc[rr];
    } else {
      if (j0 + 4 <= N) {
        *reinterpret_cast<float2*>(&out[obase]) = make_float2(acc[rr].x, acc[rr].y);
        *reinterpret_cast<float2*>(&out[obase + 2]) = make_float2(acc[rr].z, acc[rr].w);
      } else {
        float v[4] = {acc[rr].x, acc[rr].y, acc[rr].z, acc[rr].w};
        #pragma unroll
        for (int jj = 0; jj < 4; ++jj)
          if (j0 + jj < N) out[obase + jj] = v[jj];
      }
    }
  }
}

// ---------------------------------------------------------------------------
// R0: fused scan H=16 (4 rows, 1 wave) + proj to HN=32.  Slab-staged I/O.
// (unchanged control)
// ---------------------------------------------------------------------------
__global__ __launch_bounds__(64) REC_ATTR
void fused_rec16(const float* __restrict__ xw, const float* __restrict__ U,
                 const float* __restrict__ Wn, const float* __restrict__ bn,
                 float* __restrict__ xwn)
{
  constexpr int H = 16, ROWS = 4, HN = 32, CH = 16, NCH = TT / CH;
  constexpr int XINR = 264;
  const int tid = threadIdx.x;
  const int r = tid >> 4, j = tid & 15;
  const int c = tid & 31, pr = tid >> 5;
  __shared__ __align__(16) float xin[2][ROWS * XINR];
  __shared__ __align__(16) float xout[ROWS * CH * HN];
  __shared__ __align__(16) float hlds[ROWS][H];

  float u[H], w[H];
  #pragma unroll
  for (int kk = 0; kk < H; ++kk) {
    u[kk] = U[kk * H + j];
    w[kk] = Wn[kk * HN + c];
    asm volatile("" : "+v"(u[kk]), "+v"(w[kk]));
  }
  const float bc = bn[c];

  const int row0 = blockIdx.x * ROWS;
  const float* gin[ROWS];
  float* gout[ROWS];
  #pragma unroll
  for (int rr = 0; rr < ROWS; ++rr) {
    gin[rr] = xw + ((size_t)(row0 + rr) * TT) * H;
    gout[rr] = xwn + ((size_t)(row0 + rr) * TT) * HN;
  }
  for (int i = tid; i < ROWS * H; i += 64) reinterpret_cast<float*>(hlds)[i] = 0.0f;
  #pragma unroll
  for (int rr = 0; rr < ROWS; ++rr) {
    float4 v = reinterpret_cast<const float4*>(gin[rr])[tid];
    *reinterpret_cast<float4*>(&xin[0][rr * XINR + tid * 4]) = v;
  }

  for (int ch = 0; ch < NCH; ++ch) {
    const int buf = ch & 1, nb = buf ^ 1;
    const int ch1 = (ch + 1 < NCH) ? ch + 1 : ch;
    float4 nv[ROWS];
    #pragma unroll
    for (int rr = 0; rr < ROWS; ++rr)
      nv[rr] = reinterpret_cast<const float4*>(gin[rr] + (size_t)ch1 * CH * H)[tid];

    #pragma unroll
    for (int s = 0; s < CH; ++s) {
      float xv = xin[buf][r * XINR + s * H + j];
      float a0 = xv, a1 = 0.0f, a2 = 0.0f, a3 = 0.0f;
      const float* hb = &hlds[r][0];
      #pragma unroll
      for (int k4 = 0; k4 < H / 4; ++k4) {
        float4 h4 = *reinterpret_cast<const float4*>(hb + 4 * k4);
        a0 = fmaf(h4.x, u[4 * k4 + 0], a0);
        a1 = fmaf(h4.y, u[4 * k4 + 1], a1);
        a2 = fmaf(h4.z, u[4 * k4 + 2], a2);
        a3 = fmaf(h4.w, u[4 * k4 + 3], a3);
      }
      float hn = tanh_fast((a0 + a1) + (a2 + a3));
      hlds[r][j] = hn;
      const float* h0b = &hlds[2 * pr + 0][0];
      const float* h1b = &hlds[2 * pr + 1][0];
      float s0 = bc, s1 = bc, s2 = 0.0f, s3 = 0.0f;
      #pragma unroll
      for (int k4 = 0; k4 < H / 4; ++k4) {
        float4 ha = *reinterpret_cast<const float4*>(h0b + 4 * k4);
        float4 hc = *reinterpret_cast<const float4*>(h1b + 4 * k4);
        s0 = fmaf(ha.x, w[4 * k4 + 0], s0);
        s2 = fmaf(ha.y, w[4 * k4 + 1], s2);
        s0 = fmaf(ha.z, w[4 * k4 + 2], s0);
        s2 = fmaf(ha.w, w[4 * k4 + 3], s2);
        s1 = fmaf(hc.x, w[4 * k4 + 0], s1);
        s3 = fmaf(hc.y, w[4 * k4 + 1], s3);
        s1 = fmaf(hc.z, w[4 * k4 + 2], s1);
        s3 = fmaf(hc.w, w[4 * k4 + 3], s3);
      }
      xout[(2 * pr + 0) * (CH * HN) + s * HN + c] = s0 + s2;
      xout[(2 * pr + 1) * (CH * HN) + s * HN + c] = s1 + s3;
    }
    #pragma unroll
    for (int rr = 0; rr < ROWS; ++rr) {
      float* gslab = gout[rr] + (size_t)(ch * CH) * HN;
      #pragma unroll
      for (int q = 0; q < 2; ++q) {
        float4 f = reinterpret_cast<const float4*>(&xout[rr * (CH * HN)])[q * 64 + tid];
        reinterpret_cast<float4*>(gslab)[q * 64 + tid] = f;
      }
    }
    #pragma unroll
    for (int rr = 0; rr < ROWS; ++rr)
      *reinterpret_cast<float4*>(&xin[nb][rr * XINR + tid * 4]) = nv[rr];
  }
}

// ---------------------------------------------------------------------------
// R1: fused scan H=32 (2 rows, 1 wave) + proj to HN=64.  Slab-staged I/O.
// (unchanged control)
// ---------------------------------------------------------------------------
__global__ __launch_bounds__(64) REC_ATTR
void fused_rec32(const float* __restrict__ xw, const float* __restrict__ U,
                 const float* __restrict__ Wn, const float* __restrict__ bn,
                 float* __restrict__ xwn)
{
  constexpr int H = 32, ROWS = 2, HN = 64, CH = 16, NCH = TT / CH;
  constexpr int XINR = 520;
  const int tid = threadIdx.x;
  const int r = tid >> 5, j = tid & 31;
  const int c = tid;
  __shared__ __align__(16) float xin[2][ROWS * XINR];
  __shared__ __align__(16) float xout[ROWS * CH * HN];
  __shared__ __align__(16) float hlds[ROWS][H];

  float u[H], w[H];
  #pragma unroll
  for (int kk = 0; kk < H; ++kk) {
    u[kk] = U[kk * H + j];
    w[kk] = Wn[kk * HN + c];
    asm volatile("" : "+v"(u[kk]), "+v"(w[kk]));
  }
  const float bc = bn[c];

  const int row0 = blockIdx.x * ROWS;
  const float* gin[ROWS];
  float* gout[ROWS];
  #pragma unroll
  for (int rr = 0; rr < ROWS; ++rr) {
    gin[rr] = xw + ((size_t)(row0 + rr) * TT) * H;
    gout[rr] = xwn + ((size_t)(row0 + rr) * TT) * HN;
  }
  for (int i = tid; i < ROWS * H; i += 64) reinterpret_cast<float*>(hlds)[i] = 0.0f;
  #pragma unroll
  for (int rr = 0; rr < ROWS; ++rr)
    #pragma unroll
    for (int q = 0; q < 2; ++q) {
      float4 v = reinterpret_cast<const float4*>(gin[rr])[q * 64 + tid];
      *reinterpret_cast<float4*>(&xin[0][rr * XINR + (q * 64 + tid) * 4]) = v;
    }

  for (int ch = 0; ch < NCH; ++ch) {
    const int buf = ch & 1, nb = buf ^ 1;
    const int ch1 = (ch + 1 < NCH) ? ch + 1 : ch;
    float4 nv[ROWS][2];
    #pragma unroll
    for (int rr = 0; rr < ROWS; ++rr)
      #pragma unroll
      for (int q = 0; q < 2; ++q)
        nv[rr][q] = reinterpret_cast<const float4*>(gin[rr] + (size_t)ch1 * CH * H)[q * 64 + tid];

    #pragma unroll
    for (int s = 0; s < CH; ++s) {
      float xv = xin[buf][r * XINR + s * H + j];
      float a0 = xv, a1 = 0.0f, a2 = 0.0f, a3 = 0.0f;
      const float* hb = &hlds[r][0];
      #pragma unroll
      for (int k4 = 0; k4 < H / 4; ++k4) {
        float4 h4 = *reinterpret_cast<const float4*>(hb + 4 * k4);
        a0 = fmaf(h4.x, u[4 * k4 + 0], a0);
        a1 = fmaf(h4.y, u[4 * k4 + 1], a1);
        a2 = fmaf(h4.z, u[4 * k4 + 2], a2);
        a3 = fmaf(h4.w, u[4 * k4 + 3], a3);
      }
      float hn = tanh_fast((a0 + a1) + (a2 + a3));
      hlds[r][j] = hn;
      const float* h0b = &hlds[0][0];
      const float* h1b = &hlds[1][0];
      float s0 = bc, s1 = bc, s2 = 0.0f, s3 = 0.0f;
      #pragma unroll
      for (int k4 = 0; k4 < H / 4; ++k4) {
        float4 ha = *reinterpret_cast<const float4*>(h0b + 4 * k4);
        float4 hc = *reinterpret_cast<const float4*>(h1b + 4 * k4);
        s0 = fmaf(ha.x, w[4 * k4 + 0], s0);
        s2 = fmaf(ha.y, w[4 * k4 + 1], s2);
        s0 = fmaf(ha.z, w[4 * k4 + 2], s0);
        s2 = fmaf(ha.w, w[4 * k4 + 3], s2);
        s1 = fmaf(hc.x, w[4 * k4 + 0], s1);
        s3 = fmaf(hc.y, w[4 * k4 + 1], s3);
        s1 = fmaf(hc.z, w[4 * k4 + 2], s1);
        s3 = fmaf(hc.w, w[4 * k4 + 3], s3);
      }
      xout[0 * (CH * HN) + s * HN + c] = s0 + s2;
      xout[1 * (CH * HN) + s * HN + c] = s1 + s3;
    }
    #pragma unroll
    for (int rr = 0; rr < ROWS; ++rr) {
      float* gslab = gout[rr] + (size_t)(ch * CH) * HN;
      #pragma unroll
      for (int q = 0; q < 4; ++q) {
        float4 f = reinterpret_cast<const float4*>(&xout[rr * (CH * HN)])[q * 64 + tid];
        reinterpret_cast<float4*>(gslab)[q * 64 + tid] = f;
      }
    }
    #pragma unroll
    for (int rr = 0; rr < ROWS; ++rr)
      #pragma unroll
      for (int q = 0; q < 2; ++q)
        *reinterpret_cast<float4*>(&xin[nb][rr * XINR + (q * 64 + tid) * 4]) = nv[rr][q];
  }
}

// ---------------------------------------------------------------------------
// rec64: scan H=64, R=2 rows per single wave -- two independent chains
// interleaved for ILP.  Slab-staged input and h-sequence output; per-chunk
// xv hoisted to registers (removes one dependent DS read from the chain).
// ---------------------------------------------------------------------------
__global__ __launch_bounds__(64) REC_ATTR
void rec64_kernel(const float* __restrict__ xw, const float* __restrict__ U,
                  float* __restrict__ hseq)
{
  constexpr int H = 64, CH = 16, NCH = TT / CH;
  const int tid = threadIdx.x;
  const int rowA = blockIdx.x * 2, rowB = rowA + 1;
  __shared__ __align__(16) float xinA[2][CH * H], xinB[2][CH * H];
  __shared__ __align__(16) float xoutA[CH * H], xoutB[CH * H];
  __shared__ __align__(16) float hA[H], hB[H];

  float u[H];
  #pragma unroll
  for (int kk = 0; kk < H; ++kk) {
    u[kk] = U[kk * H + tid];
    asm volatile("" : "+v"(u[kk]));
  }
  const float* ginA = xw + ((size_t)rowA * TT) * H;
  const float* ginB = xw + ((size_t)rowB * TT) * H;
  float* goutA = hseq + ((size_t)rowA * TT) * H;
  float* goutB = hseq + ((size_t)rowB * TT) * H;

  hA[tid] = 0.0f;
  hB[tid] = 0.0f;
  #pragma unroll
  for (int q = 0; q < 4; ++q) {
    *reinterpret_cast<float4*>(&xinA[0][(q * 64 + tid) * 4]) =
        reinterpret_cast<const float4*>(ginA)[q * 64 + tid];
    *reinterpret_cast<float4*>(&xinB[0][(q * 64 + tid) * 4]) =
        reinterpret_cast<const float4*>(ginB)[q * 64 + tid];
  }

  for (int ch = 0; ch < NCH; ++ch) {
    const int buf = ch & 1, nb = buf ^ 1;
    const int ch1 = (ch + 1 < NCH) ? ch + 1 : ch;
    float4 nvA[4], nvB[4];
    #pragma unroll
    for (int q = 0; q < 4; ++q) {
      nvA[q] = reinterpret_cast<const float4*>(ginA + (size_t)ch1 * CH * H)[q * 64 + tid];
      nvB[q] = reinterpret_cast<const float4*>(ginB + (size_t)ch1 * CH * H)[q * 64 + tid];
    }
    // hoist this chunk's xv values into registers (pipelined ds_reads)
    float xvA[CH], xvB[CH];
    #pragma unroll
    for (int s = 0; s < CH; ++s) {
      xvA[s] = xinA[buf][s * H + tid];
      xvB[s] = xinB[buf][s * H + tid];
    }

    #pragma unroll
    for (int s = 0; s < CH; ++s) {
      float a0 = xvA[s], a1 = 0.0f, a2 = 0.0f, a3 = 0.0f;
      float b0 = xvB[s], b1 = 0.0f, b2 = 0.0f, b3 = 0.0f;
      #pragma unroll
      for (int k4 = 0; k4 < H / 4; ++k4) {
        float4 h4a = *reinterpret_cast<const float4*>(&hA[4 * k4]);
        float4 h4b = *reinterpret_cast<const float4*>(&hB[4 * k4]);
        a0 = fmaf(h4a.x, u[4 * k4 + 0], a0);
        a1 = fmaf(h4a.y, u[4 * k4 + 1], a1);
        a2 = fmaf(h4a.z, u[4 * k4 + 2], a2);
        a3 = fmaf(h4a.w, u[4 * k4 + 3], a3);
        b0 = fmaf(h4b.x, u[4 * k4 + 0], b0);
        b1 = fmaf(h4b.y, u[4 * k4 + 1], b1);
        b2 = fmaf(h4b.z, u[4 * k4 + 2], b2);
        b3 = fmaf(h4b.w, u[4 * k4 + 3], b3);
      }
      float hnA = tanh_fast((a0 + a1) + (a2 + a3));
      float hnB = tanh_fast((b0 + b1) + (b2 + b3));
      hA[tid] = hnA;
      hB[tid] = hnB;
      xoutA[s * H + tid] = hnA;
      xoutB[s * H + tid] = hnB;
    }
    float* gsA = goutA + (size_t)(ch * CH) * H;
    float* gsB = goutB + (size_t)(ch * CH) * H;
    #pragma unroll
    for (int q = 0; q < 4; ++q) {
      reinterpret_cast<float4*>(gsA)[q * 64 + tid] =
          reinterpret_cast<const float4*>(xoutA)[q * 64 + tid];
      reinterpret_cast<float4*>(gsB)[q * 64 + tid] =
          reinterpret_cast<const float4*>(xoutB)[q * 64 + tid];
    }
    #pragma unroll
    for (int q = 0; q < 4; ++q) {
      *reinterpret_cast<float4*>(&xinA[nb][(q * 64 + tid) * 4]) = nvA[q];
      *reinterpret_cast<float4*>(&xinB[nb][(q * 64 + tid) * 4]) = nvB[q];
    }
  }
}

// ---------------------------------------------------------------------------
// rec70: 2-wave block, R=2 rows per block.  Every active thread (tid<70 ...
// pattern j=tid%...; here j = tid if tid<70) computes column j for BOTH rows
// -- two independent chains for ILP.  h double-buffered in LDS, one
// lgkmcnt+s_barrier per step (serves both rows).  Slab-staged xw, xv hoisted.
// Fused dense(70->5) + softmax for both rows (one per wave).
// ---------------------------------------------------------------------------
__global__ __launch_bounds__(128) REC_ATTR
void rec70_kernel(const float* __restrict__ xw, const float* __restrict__ U,
                  const float* __restrict__ Wd, const float* __restrict__ bd,
                  float* __restrict__ outp)
{
  constexpr int H = 70, HP = 72, CH = 16, NCH = TT / CH, SLAB = CH * H;  // 1120
  constexpr int NL = 9;  // ceil(1120/128)
  const int tid = threadIdx.x;
  const int rowA = blockIdx.x * 2;
  const bool act = tid < H;
  const int j = act ? tid : 0;

  __shared__ __align__(16) float xinA[2][1152], xinB[2][1152];
  __shared__ __align__(16) float hbufA[2][HP], hbufB[2][HP];

  float u[HP];
  #pragma unroll
  for (int kk = 0; kk < HP; ++kk) {
    u[kk] = (kk < H && act) ? U[kk * H + j] : 0.0f;
    asm volatile("" : "+v"(u[kk]));
  }

  const float* ginA = xw + ((size_t)rowA * TT) * H;
  const float* ginB = xw + ((size_t)(rowA + 1) * TT) * H;
  for (int i = tid; i < 2 * HP; i += 128) {
    reinterpret_cast<float*>(hbufA)[i] = 0.0f;
    reinterpret_cast<float*>(hbufB)[i] = 0.0f;
  }
  #pragma unroll
  for (int q = 0; q < NL; ++q) {
    int idx = q * 128 + tid;
    xinA[0][idx] = (idx < SLAB) ? ginA[idx] : 0.0f;
    xinB[0][idx] = (idx < SLAB) ? ginB[idx] : 0.0f;
  }
  __syncthreads();  // once, pre-loop

  for (int ch = 0; ch < NCH; ++ch) {
    const int buf = ch & 1, nb = buf ^ 1;
    const int ch1 = (ch + 1 < NCH) ? ch + 1 : ch;
    float nvA[NL], nvB[NL];
    #pragma unroll
    for (int q = 0; q < NL; ++q) {
      int idx = q * 128 + tid;
      nvA[q] = (idx < SLAB) ? (ginA + (size_t)ch1 * SLAB)[idx] : 0.0f;
      nvB[q] = (idx < SLAB) ? (ginB + (size_t)ch1 * SLAB)[idx] : 0.0f;
    }
    float xvA[CH], xvB[CH];
    #pragma unroll
    for (int s = 0; s < CH; ++s) {
      xvA[s] = xinA[buf][s * H + j];
      xvB[s] = xinB[buf][s * H + j];
    }

    #pragma unroll
    for (int s = 0; s < CH; ++s) {
      const float* hbA = &hbufA[s & 1][0];
      const float* hbB = &hbufB[s & 1][0];
      float a0 = xvA[s], a1 = 0.0f, a2 = 0.0f, a3 = 0.0f;
      float b0 = xvB[s], b1 = 0.0f, b2 = 0.0f, b3 = 0.0f;
      #pragma unroll
      for (int k4 = 0; k4 < HP / 4; ++k4) {
        float4 h4a = *reinterpret_cast<const float4*>(hbA + 4 * k4);
        float4 h4b = *reinterpret_cast<const float4*>(hbB + 4 * k4);
        a0 = fmaf(h4a.x, u[4 * k4 + 0], a0);
        a1 = fmaf(h4a.y, u[4 * k4 + 1], a1);
        a2 = fmaf(h4a.z, u[4 * k4 + 2], a2);
        a3 = fmaf(h4a.w, u[4 * k4 + 3], a3);
        b0 = fmaf(h4b.x, u[4 * k4 + 0], b0);
        b1 = fmaf(h4b.y, u[4 * k4 + 1], b1);
        b2 = fmaf(h4b.z, u[4 * k4 + 2], b2);
        b3 = fmaf(h4b.w, u[4 * k4 + 3], b3);
      }
      float hnA = tanh_fast((a0 + a1) + (a2 + a3));
      float hnB = tanh_fast((b0 + b1) + (b2 + b3));
      if (act) {
        hbufA[(s & 1) ^ 1][j] = hnA;
        hbufB[(s & 1) ^ 1][j] = hnB;
      }
      if (s == CH - 1) {  // stage next slabs just before the chunk-boundary barrier
        #pragma unroll
        for (int q = 0; q < NL; ++q) {
          xinA[nb][q * 128 + tid] = nvA[q];
          xinB[nb][q * 128 + tid] = nvB[q];
        }
      }
      LDS_BARRIER();
    }
  }

  // final h in hbufA[0]/hbufB[0].  Dense (70->5) + softmax: wave 0 -> row A,
  // wave 1 -> row B (shfl stays within each wave).
  const int wv = tid >> 6, lane = tid & 63;
  const float* hb = wv ? &hbufB[0][0] : &hbufA[0][0];
  float l = 0.0f;
  if (lane < 5) {
    l = bd[lane];
    #pragma unroll
    for (int kk = 0; kk < H; ++kk)
      l = fmaf(hb[kk], Wd[kk * 5 + lane], l);
  }
  float l0 = __shfl(l, 0), l1 = __shfl(l, 1), l2 = __shfl(l, 2),
        l3 = __shfl(l, 3), l4 = __shfl(l, 4);
  float m = fmaxf(fmaxf(fmaxf(l0, l1), fmaxf(l2, l3)), l4);
  float s = __expf(l0 - m) + __expf(l1 - m) + __expf(l2 - m) +
            __expf(l3 - m) + __expf(l4 - m);
  if (lane < 5)
    outp[(size_t)(rowA + wv) * 5 + lane] = __expf(l - m) / s;
}

extern "C" void kernel_launch(void* const* d_in, const int* in_sizes, int n_in,
                              void* d_out, int out_size, void* d_ws, size_t ws_size,
                              hipStream_t stream)
{
  const float* x  = (const float*)d_in[0];
  const float* W0 = (const float*)d_in[1];
  const float* U0 = (const float*)d_in[2];
  const float* b0 = (const float*)d_in[3];
  const float* W1 = (const float*)d_in[4];
  const float* U1 = (const float*)d_in[5];
  const float* b1 = (const float*)d_in[6];
  const float* W2 = (const float*)d_in[7];
  const float* U2 = (const float*)d_in[8];
  const float* b2 = (const float*)d_in[9];
  const float* W3 = (const float*)d_in[10];
  const float* U3 = (const float*)d_in[11];
  const float* b3 = (const float*)d_in[12];
  const float* Wd = (const float*)d_in[13];
  const float* bd = (const float*)d_in[14];
  float* outp = (float*)d_out;

  // A: xw0 [M,16] -> xw2 [M,64] -> xw3 [M,70] (73,400,320 B)
  // Bv: xw1 [M,32] -> h2 [M,64]               (67,108,864 B)
  float* A  = (float*)d_ws;
  float* Bv = (float*)((char*)d_ws + 73400320);

  const int M = M_TOTAL;

  // xw0 = x @ W0 + b0
  proj_kernel<78, 16, 4><<<M / 256, 256, 0, stream>>>(x, W0, b0, A, M);
  // scan L0 + fused xw1 = h0 @ W1 + b1
  fused_rec16<<<BB / 4, 64, 0, stream>>>(A, U0, W1, b1, Bv);
  // scan L1 + fused xw2 = h1 @ W2 + b2
  fused_rec32<<<BB / 2, 64, 0, stream>>>(Bv, U1, W2, b2, A);
  // scan L2 -> h2 sequence (R=2 rows/wave)
  rec64_kernel<<<BB / 2, 64, 0, stream>>>(A, U2, Bv);
  // xw3 = h2 @ W3 + b3
  proj_kernel<64, 70, 18><<<(M + 55) / 56, 256, 0, stream>>>(Bv, W3, b3, A, M);
  // scan L3 (2-wave, R=2 rows/block) + dense + softmax
  rec70_kernel<<<BB / 2, 128, 0, stream>>>(A, U3, Wd, bd, outp);
}